// Round 15
// baseline (357.642 us; speedup 1.0000x reference)
//
#include <hip/hip_runtime.h>
#include <stdint.h>

// Problem constants (from reference setup_inputs)
#define M_TOK 8192
#define N_OUT 4096
#define K_IN  4096

// INT8 GEMM: 256x256 tile, BK=128, double-buffered LDS (128 KiB),
// 4 waves in 2x2, each owning a 128x128 output tile (acc[8][8]).
// 1 wave/SIMD: ILP-pipelined (reads issued before each MFMA burst).
#define BM 256
#define BN 256
#define BK 128
#define NT (K_IN / BK)            // 32 K-tiles
#define SEC 16384                 // bytes per k-slice section (256 rows x 64 B)
#define BUF 65536                 // bytes per buffer (A_s0|A_s1|B_s0|B_s1)

typedef int intx4 __attribute__((ext_vector_type(4)));

#define MFMAI8 __builtin_amdgcn_mfma_i32_16x16x64_i8

// ---------- helpers ----------

// async global->LDS, 16 bytes per lane. LDS side is wave-uniform base + lane*16.
__device__ __forceinline__ void async_copy16(const void* g, void* l) {
    __builtin_amdgcn_global_load_lds(
        (__attribute__((address_space(1))) void*)(g),
        (__attribute__((address_space(3))) void*)(l),
        16, 0, 0);
}

// ---------- pre-pass 1: x fp32 -> int8 per-token (sx = rowmax/127, RNE) ----------

__global__ void quant_x_kernel(const float* __restrict__ in,
                               int8_t* __restrict__ out,
                               float* __restrict__ sx) {
    const int row = blockIdx.x;
    const int tid = threadIdx.x;
    const float4* p = (const float4*)(in + (size_t)row * K_IN + tid * 16);
    float4 v0 = p[0], v1 = p[1], v2 = p[2], v3 = p[3];

    float m = fabsf(v0.x);
    m = fmaxf(m, fabsf(v0.y)); m = fmaxf(m, fabsf(v0.z)); m = fmaxf(m, fabsf(v0.w));
    m = fmaxf(m, fabsf(v1.x)); m = fmaxf(m, fabsf(v1.y));
    m = fmaxf(m, fabsf(v1.z)); m = fmaxf(m, fabsf(v1.w));
    m = fmaxf(m, fabsf(v2.x)); m = fmaxf(m, fabsf(v2.y));
    m = fmaxf(m, fabsf(v2.z)); m = fmaxf(m, fabsf(v2.w));
    m = fmaxf(m, fabsf(v3.x)); m = fmaxf(m, fabsf(v3.y));
    m = fmaxf(m, fabsf(v3.z)); m = fmaxf(m, fabsf(v3.w));

#pragma unroll
    for (int off = 32; off; off >>= 1) m = fmaxf(m, __shfl_xor(m, off));
    __shared__ float wmax[4];
    if ((tid & 63) == 0) wmax[tid >> 6] = m;
    __syncthreads();
    m = fmaxf(fmaxf(wmax[0], wmax[1]), fmaxf(wmax[2], wmax[3]));
    m = fmaxf(m, 1e-20f);

    const float rs = 127.0f / m;
    if (tid == 0) sx[row] = m * (1.0f / 127.0f);

    union { int4 v; int8_t c[16]; } u;
    u.c[0]  = (int8_t)__float2int_rn(v0.x * rs);
    u.c[1]  = (int8_t)__float2int_rn(v0.y * rs);
    u.c[2]  = (int8_t)__float2int_rn(v0.z * rs);
    u.c[3]  = (int8_t)__float2int_rn(v0.w * rs);
    u.c[4]  = (int8_t)__float2int_rn(v1.x * rs);
    u.c[5]  = (int8_t)__float2int_rn(v1.y * rs);
    u.c[6]  = (int8_t)__float2int_rn(v1.z * rs);
    u.c[7]  = (int8_t)__float2int_rn(v1.w * rs);
    u.c[8]  = (int8_t)__float2int_rn(v2.x * rs);
    u.c[9]  = (int8_t)__float2int_rn(v2.y * rs);
    u.c[10] = (int8_t)__float2int_rn(v2.z * rs);
    u.c[11] = (int8_t)__float2int_rn(v2.w * rs);
    u.c[12] = (int8_t)__float2int_rn(v3.x * rs);
    u.c[13] = (int8_t)__float2int_rn(v3.y * rs);
    u.c[14] = (int8_t)__float2int_rn(v3.z * rs);
    u.c[15] = (int8_t)__float2int_rn(v3.w * rs);
    ((int4*)(out + (size_t)row * K_IN))[tid] = u.v;
}

// ---------- pre-pass 2: W int32 (int8-valued) -> int8 pack (EXACT) ----------

__global__ void quant_w_kernel(const int* __restrict__ in,
                               int8_t* __restrict__ out, int n16) {
    int i = blockIdx.x * 256 + threadIdx.x;   // handles 16 elements
    if (i >= n16) return;
    const int4* p = (const int4*)in + (size_t)i * 4;
    int4 a = p[0], b = p[1], c = p[2], d = p[3];
    union { int4 v; int8_t q[16]; } u;
    u.q[0]  = (int8_t)a.x; u.q[1]  = (int8_t)a.y; u.q[2]  = (int8_t)a.z; u.q[3]  = (int8_t)a.w;
    u.q[4]  = (int8_t)b.x; u.q[5]  = (int8_t)b.y; u.q[6]  = (int8_t)b.z; u.q[7]  = (int8_t)b.w;
    u.q[8]  = (int8_t)c.x; u.q[9]  = (int8_t)c.y; u.q[10] = (int8_t)c.z; u.q[11] = (int8_t)c.w;
    u.q[12] = (int8_t)d.x; u.q[13] = (int8_t)d.y; u.q[14] = (int8_t)d.z; u.q[15] = (int8_t)d.w;
    ((int4*)out)[i] = u.v;
}

// ---------- GEMM: C[m][n] = sx[m]*scales[n]*(sum_k xq*wq) + bias[n] ----------
// BIG-WAVE-TILE variant of R14 (which measured 140us, absmax 4.5): 4 waves
// own 128x128 each (2x2 grid) -> LDS read amplification 3x -> 2x (192->128
// KiB/tile) with MFMA work unchanged. 1 wave/SIMD; ILP pipelining: each
// phase ISSUES its ds_reads before the MFMA burst, so the DS pipe services
// them under the matrix stream (issue-then-compute, no TLP needed).
//
// R14's verified 4-phase single-sync ledger, rescaled (reads 4/12/4/12-ish,
// waits all <= 15 = lgkmcnt encoding limit):
//  P1: stage A(t+1) s0+s1 (8 gl) | read af47X (4) |
//      lgkm(4)  [drains af03X + bfX (12 oldest)] | 32 MFMA (af03X x bfX)
//  P2: stage B(t+1) s0+s1 (8 gl) | read af03Y + bfY (12) |
//      lgkm(12) [drains af47X] | 32 MFMA (af47X x bfX)
//  P3: read af47Y (4) | lgkm(4) [drains af03Y + bfY] | 32 MFMA (af03Y x bfY)
//  P4: vmcnt(0)+lgkm(0) [stages issued 2-3 phases ago; drains af47Y] |
//      BARRIER | read af03X' + bfX' (12, next buf) | 32 MFMA (af47Y x bfY)
// Hazards (R6/R14 pattern): all buf(t) reads lgkm-drained before the
// boundary barrier; stage(t+2) issues after it; buf(t+1) reads follow every
// wave's vmcnt(0)+barrier; cross-barrier outstanding reads target buf(t+1),
// disjoint from stage(t+2). Integer accumulation exact -> absmax identical
// to R14 (4.5) regardless of acc order.
//
// LDS: byte sections A_s0|A_s1|B_s0|B_s1 (16 KiB each = 256 rows x 64 B),
// PAIR-ROW swizzle (0 conflicts, HW-verified R3/R4/R14): pair p = row>>1
// (128 B) holds rows {2p,2p+1}; 16 B chunk (p,c): cg = c ^ (p&7); inverse on
// the per-lane GLOBAL source, linear LDS dest. Every ds_read_b128 covers one
// contiguous 1 KiB window exactly once.

__global__ __launch_bounds__(256, 1)
void gemm_i8_kernel(const int8_t* __restrict__ A,
                    const int8_t* __restrict__ B,
                    const float* __restrict__ sx,
                    const float* __restrict__ scales,
                    const float* __restrict__ bias,
                    float* __restrict__ C) {
    __shared__ __align__(16) int8_t lds[2 * BUF];   // 128 KiB

    const int tid = threadIdx.x;

    // T1: bijective XCD swizzle (nwg = 512, divisible by 8), bn-fastest.
    const int nwg = (M_TOK / BM) * (N_OUT / BN);   // 32*16 = 512
    const int cpx = nwg / 8;                        // 64
    const int wg  = (blockIdx.x % 8) * cpx + blockIdx.x / 8;
    const int bn  = wg & 15;                        // N_OUT/BN = 16
    const int bm  = wg >> 4;                        // 0..31

    const int lane = tid & 63;
    const int wave = tid >> 6;          // 0..3
    const int wm   = wave >> 1;         // 0..1 -> rows wm*128
    const int wn   = wave & 1;          // 0..1 -> cols wn*128

    // ---- staging addressing (pair-row inverse swizzle, bytes) ----
    // One issue = 256 lanes x 16 B = 4 KiB = 32 pairs = 64 rows of a 64B slice.
    const int t8 = tid >> 3;                        // 0..31 (pair in issue)
    const int cg = (tid & 7) ^ (t8 & 7);            // unswizzled chunk in pair
    const int grow0 = 2 * t8 + (cg >> 2);           // row within 64-row issue
    const int gcol0 = (cg & 3) * 16;                // bytes within 64B slice
    const int8_t* aP = A + (size_t)(bm * BM + grow0) * K_IN + gcol0;
    const int8_t* bP = B + (size_t)(bn * BN + grow0) * K_IN + gcol0;

    auto stA = [&](int tt, int s) {   // one 256-row slice = 4 issues
        int8_t* d = &lds[(tt & 1) * BUF + s * SEC + tid * 16];
        const int8_t* g = aP + (size_t)tt * BK + s * 64;
#pragma unroll
        for (int i = 0; i < 4; ++i)
            async_copy16(g + (size_t)i * 64 * K_IN, d + i * 4096);
    };
    auto stB = [&](int tt, int s) {
        int8_t* d = &lds[(tt & 1) * BUF + 2 * SEC + s * SEC + tid * 16];
        const int8_t* g = bP + (size_t)tt * BK + s * 64;
#pragma unroll
        for (int i = 0; i < 4; ++i)
            async_copy16(g + (size_t)i * 64 * K_IN, d + i * 4096);
    };

    // ---- fragment read addressing ----
    // Frag row R: pair p = R>>1, chunk c = ((R&1)*4 + q) ^ ((R>>1)&7), 16 B.
    const int r16 = lane & 15;
    const int q   = lane >> 4;                      // k-chunk (16 B) in slice
    const int cr  = (((r16 & 1) << 2) + q) ^ ((r16 >> 1) & 7);
    const int aOff = (wm * 64 + (r16 >> 1)) * 128 + cr * 16;
    const int bOff = 2 * SEC + (wn * 64 + (r16 >> 1)) * 128 + cr * 16;

    intx4 acc[8][8] = {};
    intx4 af03X[4], af47X[4], af03Y[4], af47Y[4];
    intx4 bfX[8], bfY[8];

#define RD_A03(dst, base, s)                                                   \
    { _Pragma("unroll") for (int i = 0; i < 4; ++i)                            \
        dst[i] = *(const intx4*)((base) + (s) * SEC + aOff + i * 1024); }
#define RD_A47(dst, base, s)                                                   \
    { _Pragma("unroll") for (int i = 0; i < 4; ++i)                            \
        dst[i] = *(const intx4*)((base) + (s) * SEC + aOff + (4 + i) * 1024); }
#define RD_B8(dst, base, s)                                                    \
    { _Pragma("unroll") for (int j = 0; j < 8; ++j)                            \
        dst[j] = *(const intx4*)((base) + (s) * SEC + bOff + j * 1024); }
#define MM03(af, bf)                                                           \
    { __builtin_amdgcn_s_setprio(1);                                           \
      _Pragma("unroll") for (int i = 0; i < 4; ++i)                            \
          _Pragma("unroll") for (int j = 0; j < 8; ++j)                        \
              acc[i][j] = MFMAI8(af[i], bf[j], acc[i][j], 0, 0, 0);            \
      __builtin_amdgcn_s_setprio(0); }
#define MM47(af, bf)                                                           \
    { __builtin_amdgcn_s_setprio(1);                                           \
      _Pragma("unroll") for (int i = 0; i < 4; ++i)                            \
          _Pragma("unroll") for (int j = 0; j < 8; ++j)                        \
              acc[4 + i][j] = MFMAI8(af[i], bf[j], acc[4 + i][j], 0, 0, 0);    \
      __builtin_amdgcn_s_setprio(0); }
#define SBAR __builtin_amdgcn_sched_barrier(0)

    // ---- prologue: stage tile 0 (16 gl), publish, read af03X+bfX (12) ----
    stA(0, 0); stA(0, 1); stB(0, 0); stB(0, 1);
    asm volatile("s_waitcnt vmcnt(0)" ::: "memory");
    __builtin_amdgcn_s_barrier();
    asm volatile("" ::: "memory");
    RD_A03(af03X, lds, 0);
    RD_B8(bfX, lds, 0);

#pragma unroll 1
    for (int t = 0; t < NT; ++t) {
        const int8_t* Lb  = lds + (t & 1) * BUF;
        const int8_t* Lb2 = lds + ((t + 1) & 1) * BUF;
        const bool pf = (t + 1 < NT);

        // ---- P1: stage A(t+1) | read af47X | MM(af03X, bfX) ----
        if (pf) { stA(t + 1, 0); stA(t + 1, 1); }
        RD_A47(af47X, Lb, 0);
        asm volatile("s_waitcnt lgkmcnt(4)" ::: "memory");   // af03X+bfX ready
        SBAR;
        MM03(af03X, bfX);

        // ---- P2: stage B(t+1) | read af03Y+bfY | MM(af47X, bfX) ----
        if (pf) { stB(t + 1, 0); stB(t + 1, 1); }
        RD_A03(af03Y, Lb, 1);
        RD_B8(bfY, Lb, 1);
        asm volatile("s_waitcnt lgkmcnt(12)" ::: "memory");  // af47X ready
        SBAR;
        MM47(af47X, bfX);

        // ---- P3: read af47Y | MM(af03Y, bfY) ----
        RD_A47(af47Y, Lb, 1);
        asm volatile("s_waitcnt lgkmcnt(4)" ::: "memory");   // af03Y+bfY ready
        SBAR;
        MM03(af03Y, bfY);

        // ---- P4: boundary sync | read next af03X+bfX | MM(af47Y, bfY) ----
        asm volatile("s_waitcnt vmcnt(0) lgkmcnt(0)" ::: "memory");
        __builtin_amdgcn_s_barrier();
        asm volatile("" ::: "memory");
        if (pf) {
            RD_A03(af03X, Lb2, 0);
            RD_B8(bfX, Lb2, 0);
        }
        SBAR;
        MM47(af47Y, bfY);
    }

    // ---- epilogue: C/D col = lane&15, row = (lane>>4)*4 + reg (dtype-indep) ----
    const int row0 = bm * BM + wm * 128 + q * 4;
    const int col0 = bn * BN + wn * 128 + r16;
    float sxv[8][4];
#pragma unroll
    for (int fr = 0; fr < 8; ++fr)
#pragma unroll
        for (int r = 0; r < 4; ++r)
            sxv[fr][r] = sx[row0 + fr * 16 + r];
#pragma unroll
    for (int fc = 0; fc < 8; ++fc) {
        const int n  = col0 + fc * 16;
        const float sc = scales[n];
        const float bi = bias[n];
#pragma unroll
        for (int fr = 0; fr < 8; ++fr) {
            const int m = row0 + fr * 16;
#pragma unroll
            for (int r = 0; r < 4; ++r)
                C[(size_t)(m + r) * N_OUT + n] =
                    (float)acc[fr][fc][r] * (sxv[fr][r] * sc) + bi;
        }
    }
}

// ---------- launch ----------

extern "C" void kernel_launch(void* const* d_in, const int* in_sizes, int n_in,
                              void* d_out, int out_size, void* d_ws, size_t ws_size,
                              hipStream_t stream) {
    const float* x      = (const float*)d_in[0];
    const int*   wq     = (const int*)d_in[1];
    const float* scales = (const float*)d_in[2];
    const float* bias   = (const float*)d_in[3];
    float*       out    = (float*)d_out;

    int8_t* xq = (int8_t*)d_ws;                               // 32 MiB
    int8_t* wb = xq + (size_t)M_TOK * K_IN;                   // 16 MiB
    float*  sx = (float*)(wb + (size_t)N_OUT * K_IN);         // 32 KiB
    // ws needed: 48 MiB + 32 KiB

    quant_x_kernel<<<M_TOK, 256, 0, stream>>>(x, xq, sx);
    const int nw16 = (N_OUT * K_IN) / 16;   // 1048576
    quant_w_kernel<<<nw16 / 256, 256, 0, stream>>>(wq, wb, nw16);

    const int grid = (M_TOK / BM) * (N_OUT / BN);   // 32 * 16 = 512
    gemm_i8_kernel<<<grid, 256, 0, stream>>>(xq, wb, sx, scales, bias, out);
}

// Round 16
// 198.488 us; speedup vs baseline: 1.8018x; 1.8018x over previous
//
#include <hip/hip_runtime.h>
#include <stdint.h>

// Problem constants (from reference setup_inputs)
#define M_TOK 8192
#define N_OUT 4096
#define K_IN  4096

// INT8 GEMM: 256x256 tile, BK=64, 3-buffer LDS ring (96 KiB), 8 waves 2x4.
// Counted vmcnt(4) at tile boundaries -- DMA queue never drains to 0 in the
// main loop (m218 lever, the one structural element R14 lacked).
#define BM 256
#define BN 256
#define BK 64
#define NT (K_IN / BK)            // 64 K-tiles
#define BUFS 32768                // bytes per ring buffer: A 16K | B 16K
#define BOFF 16384                // B section offset within buffer

typedef int intx4 __attribute__((ext_vector_type(4)));

#define MFMAI8 __builtin_amdgcn_mfma_i32_16x16x64_i8

// ---------- helpers ----------

// async global->LDS, 16 bytes per lane. LDS side is wave-uniform base + lane*16.
__device__ __forceinline__ void async_copy16(const void* g, void* l) {
    __builtin_amdgcn_global_load_lds(
        (__attribute__((address_space(1))) void*)(g),
        (__attribute__((address_space(3))) void*)(l),
        16, 0, 0);
}

// ---------- pre-pass 1: x fp32 -> int8 per-token (sx = rowmax/127, RNE) ----------

__global__ void quant_x_kernel(const float* __restrict__ in,
                               int8_t* __restrict__ out,
                               float* __restrict__ sx) {
    const int row = blockIdx.x;
    const int tid = threadIdx.x;
    const float4* p = (const float4*)(in + (size_t)row * K_IN + tid * 16);
    float4 v0 = p[0], v1 = p[1], v2 = p[2], v3 = p[3];

    float m = fabsf(v0.x);
    m = fmaxf(m, fabsf(v0.y)); m = fmaxf(m, fabsf(v0.z)); m = fmaxf(m, fabsf(v0.w));
    m = fmaxf(m, fabsf(v1.x)); m = fmaxf(m, fabsf(v1.y));
    m = fmaxf(m, fabsf(v1.z)); m = fmaxf(m, fabsf(v1.w));
    m = fmaxf(m, fabsf(v2.x)); m = fmaxf(m, fabsf(v2.y));
    m = fmaxf(m, fabsf(v2.z)); m = fmaxf(m, fabsf(v2.w));
    m = fmaxf(m, fabsf(v3.x)); m = fmaxf(m, fabsf(v3.y));
    m = fmaxf(m, fabsf(v3.z)); m = fmaxf(m, fabsf(v3.w));

#pragma unroll
    for (int off = 32; off; off >>= 1) m = fmaxf(m, __shfl_xor(m, off));
    __shared__ float wmax[4];
    if ((tid & 63) == 0) wmax[tid >> 6] = m;
    __syncthreads();
    m = fmaxf(fmaxf(wmax[0], wmax[1]), fmaxf(wmax[2], wmax[3]));
    m = fmaxf(m, 1e-20f);

    const float rs = 127.0f / m;
    if (tid == 0) sx[row] = m * (1.0f / 127.0f);

    union { int4 v; int8_t c[16]; } u;
    u.c[0]  = (int8_t)__float2int_rn(v0.x * rs);
    u.c[1]  = (int8_t)__float2int_rn(v0.y * rs);
    u.c[2]  = (int8_t)__float2int_rn(v0.z * rs);
    u.c[3]  = (int8_t)__float2int_rn(v0.w * rs);
    u.c[4]  = (int8_t)__float2int_rn(v1.x * rs);
    u.c[5]  = (int8_t)__float2int_rn(v1.y * rs);
    u.c[6]  = (int8_t)__float2int_rn(v1.z * rs);
    u.c[7]  = (int8_t)__float2int_rn(v1.w * rs);
    u.c[8]  = (int8_t)__float2int_rn(v2.x * rs);
    u.c[9]  = (int8_t)__float2int_rn(v2.y * rs);
    u.c[10] = (int8_t)__float2int_rn(v2.z * rs);
    u.c[11] = (int8_t)__float2int_rn(v2.w * rs);
    u.c[12] = (int8_t)__float2int_rn(v3.x * rs);
    u.c[13] = (int8_t)__float2int_rn(v3.y * rs);
    u.c[14] = (int8_t)__float2int_rn(v3.z * rs);
    u.c[15] = (int8_t)__float2int_rn(v3.w * rs);
    ((int4*)(out + (size_t)row * K_IN))[tid] = u.v;
}

// ---------- pre-pass 2: W int32 (int8-valued) -> int8 pack (EXACT) ----------

__global__ void quant_w_kernel(const int* __restrict__ in,
                               int8_t* __restrict__ out, int n16) {
    int i = blockIdx.x * 256 + threadIdx.x;   // handles 16 elements
    if (i >= n16) return;
    const int4* p = (const int4*)in + (size_t)i * 4;
    int4 a = p[0], b = p[1], c = p[2], d = p[3];
    union { int4 v; int8_t q[16]; } u;
    u.q[0]  = (int8_t)a.x; u.q[1]  = (int8_t)a.y; u.q[2]  = (int8_t)a.z; u.q[3]  = (int8_t)a.w;
    u.q[4]  = (int8_t)b.x; u.q[5]  = (int8_t)b.y; u.q[6]  = (int8_t)b.z; u.q[7]  = (int8_t)b.w;
    u.q[8]  = (int8_t)c.x; u.q[9]  = (int8_t)c.y; u.q[10] = (int8_t)c.z; u.q[11] = (int8_t)c.w;
    u.q[12] = (int8_t)d.x; u.q[13] = (int8_t)d.y; u.q[14] = (int8_t)d.z; u.q[15] = (int8_t)d.w;
    ((int4*)out)[i] = u.v;
}

// ---------- GEMM: C[m][n] = sx[m]*scales[n]*(sum_k xq*wq) + bias[n] ----------
// R14 (140us, absmax 4.5) with the counted-vmcnt ring upgrade: BK=64, ring of
// 3 x 32 KiB buffers, stage(t+2) mid-tile, boundary wait = vmcnt(4)+lgkm(0)
// (drains stage(t+1), issued a FULL TILE earlier; stage(t+2)'s 4 loads stay
// in flight across the barrier -- never vmcnt(0) in the loop). Phases are
// 16-MFMA bursts (m201 granularity).
//
// Per-tile ledger (per wave; DS in-order; vm retires in issue order):
//  P1: read af47(t) [4 ds] | lgkm(4) [drains af03(t)+bf(t), issued prev P2] |
//      MM03 (16 MFMA)
//  P2: stage(t+2) [4 gl -> outstanding 8] |
//      vmcnt(4)+lgkm(0) [drains stage(t+1) + af47(t)] | BARRIER (publishes
//      buf(t+1)) | read af03(t+1)+bf(t+1) [8 ds, other reg set] |
//      MM47 (16 MFMA, runs with 8 reads + 4 gloads in flight)
// Tails: t=NT-2 vmcnt(0) (only stage(NT-1) outstanding); t=NT-1 lgkm(0) only.
// Ring WAR: buf(t)'s reads all lgkm-drained before tile t's barrier, which
// precedes the overwriting stage (issued tile t+1's P2) -- safe. Published
// data: every wave executes the counted drain + barrier before reading.
// Integer accumulation exact -> absmax identical to R14 (4.5) in any order.
//
// LDS buffer: A[256 rows x 64 B] | B[256 rows x 64 B]. PAIR-ROW swizzle
// (HW-verified 0 conflicts R3/R4/R14; 64-B rows identical to R14's slices):
// pair p = row>>1 (128 B) holds rows {2p,2p+1}; 16-B chunk (p,c): cg =
// c ^ (p&7); inverse on the per-lane GLOBAL source, linear LDS dest. Every
// ds_read_b128 covers one contiguous 1 KiB window exactly once.

__global__ __launch_bounds__(512, 2)
void gemm_i8_kernel(const int8_t* __restrict__ A,
                    const int8_t* __restrict__ B,
                    const float* __restrict__ sx,
                    const float* __restrict__ scales,
                    const float* __restrict__ bias,
                    float* __restrict__ C) {
    __shared__ __align__(16) int8_t lds[3 * BUFS];   // 96 KiB

    const int tid = threadIdx.x;

    // T1: bijective XCD swizzle (nwg = 512, divisible by 8), bn-fastest.
    const int nwg = (M_TOK / BM) * (N_OUT / BN);   // 32*16 = 512
    const int cpx = nwg / 8;                        // 64
    const int wg  = (blockIdx.x % 8) * cpx + blockIdx.x / 8;
    const int bn  = wg & 15;                        // N_OUT/BN = 16
    const int bm  = wg >> 4;                        // 0..31

    const int lane = tid & 63;
    const int wave = tid >> 6;          // 0..7
    const int wm   = wave >> 2;         // 0..1 -> rows wm*128
    const int wn   = wave & 3;          // 0..3 -> cols wn*64

    // ---- staging addressing (pair-row inverse swizzle, bytes) ----
    // One issue = 512 lanes x 16 B = 8 KiB = 64 pairs = 128 rows (64-B rows).
    const int t8 = tid >> 3;                        // 0..63 (pair in issue)
    const int cg = (tid & 7) ^ (t8 & 7);            // unswizzled chunk in pair
    const int grow0 = 2 * t8 + (cg >> 2);           // row within 128-row issue
    const int gcol0 = (cg & 3) * 16;                // bytes within 64-B row
    const int8_t* aP = A + (size_t)(bm * BM + grow0) * K_IN + gcol0;
    const int8_t* bP = B + (size_t)(bn * BN + grow0) * K_IN + gcol0;

    auto stage = [&](int8_t* d, int tt) {   // 4 global_load_lds (A 2, B 2)
        const int8_t* ga = aP + (size_t)tt * BK;
        async_copy16(ga, d + tid * 16);
        async_copy16(ga + (size_t)128 * K_IN, d + 8192 + tid * 16);
        const int8_t* gb = bP + (size_t)tt * BK;
        async_copy16(gb, d + BOFF + tid * 16);
        async_copy16(gb + (size_t)128 * K_IN, d + BOFF + 8192 + tid * 16);
    };

    // ---- fragment read addressing ----
    // Frag row R: pair p = R>>1, chunk c = ((R&1)*4 + q) ^ ((R>>1)&7), 16 B.
    const int r16 = lane & 15;
    const int q   = lane >> 4;                      // k-chunk (16 B = k 16)
    const int cr  = (((r16 & 1) << 2) + q) ^ ((r16 >> 1) & 7);
    const int aOff = (wm * 64 + (r16 >> 1)) * 128 + cr * 16;
    const int bOff = BOFF + (wn * 32 + (r16 >> 1)) * 128 + cr * 16;

    intx4 acc[8][4] = {};
    intx4 af03A[4], af03B[4], af47[4], bfA[4], bfB[4];

#define RD_A03(dst, base)                                                      \
    { _Pragma("unroll") for (int i = 0; i < 4; ++i)                            \
        dst[i] = *(const intx4*)((base) + aOff + i * 1024); }
#define RD_A47(dst, base)                                                      \
    { _Pragma("unroll") for (int i = 0; i < 4; ++i)                            \
        dst[i] = *(const intx4*)((base) + aOff + (4 + i) * 1024); }
#define RD_B4(dst, base)                                                       \
    { _Pragma("unroll") for (int j = 0; j < 4; ++j)                            \
        dst[j] = *(const intx4*)((base) + bOff + j * 1024); }
#define MM03(af, bf)                                                           \
    { __builtin_amdgcn_s_setprio(1);                                           \
      _Pragma("unroll") for (int i = 0; i < 4; ++i)                            \
          _Pragma("unroll") for (int j = 0; j < 4; ++j)                        \
              acc[i][j] = MFMAI8(af[i], bf[j], acc[i][j], 0, 0, 0);            \
      __builtin_amdgcn_s_setprio(0); }
#define MM47(af, bf)                                                           \
    { __builtin_amdgcn_s_setprio(1);                                           \
      _Pragma("unroll") for (int i = 0; i < 4; ++i)                            \
          _Pragma("unroll") for (int j = 0; j < 4; ++j)                        \
              acc[4 + i][j] = MFMAI8(af[i], bf[j], acc[4 + i][j], 0, 0, 0);    \
      __builtin_amdgcn_s_setprio(0); }
#define SBAR __builtin_amdgcn_sched_barrier(0)

// One K-tile: consume (af03C,bfC) from Rcur; stage t+2 into Rst; publish and
// read t+1's (af03N,bfN) from Rnxt.
#define TILE(t, af03C, bfC, af03N, bfN, Rcur, Rnxt, Rst)                       \
    {                                                                          \
        RD_A47(af47, Rcur);                                                    \
        asm volatile("s_waitcnt lgkmcnt(4)" ::: "memory");                     \
        SBAR;                                                                  \
        MM03(af03C, bfC);                                                      \
        if ((t) + 2 < NT) stage(Rst, (t) + 2);                                 \
        if ((t) + 1 < NT) {                                                    \
            if ((t) + 2 < NT)                                                  \
                asm volatile("s_waitcnt vmcnt(4) lgkmcnt(0)" ::: "memory");    \
            else                                                               \
                asm volatile("s_waitcnt vmcnt(0) lgkmcnt(0)" ::: "memory");    \
            __builtin_amdgcn_s_barrier();                                      \
            asm volatile("" ::: "memory");                                     \
            RD_A03(af03N, Rnxt);                                               \
            RD_B4(bfN, Rnxt);                                                  \
        } else {                                                               \
            asm volatile("s_waitcnt lgkmcnt(0)" ::: "memory");                 \
        }                                                                      \
        SBAR;                                                                  \
        MM47(af47, bfC);                                                       \
    }

    int8_t* r0 = lds;                // buf(t)
    int8_t* r1 = lds + BUFS;         // buf(t+1)
    int8_t* r2 = lds + 2 * BUFS;     // buf(t+2)

    // ---- prologue: stage 0,1; publish 0; read af03A+bfA (8 in flight) ----
    stage(r0, 0);
    stage(r1, 1);
    asm volatile("s_waitcnt vmcnt(4)" ::: "memory");   // stage(0) landed
    __builtin_amdgcn_s_barrier();
    asm volatile("" ::: "memory");
    RD_A03(af03A, r0);
    RD_B4(bfA, r0);

#pragma unroll 1
    for (int t = 0; t < NT; t += 2) {
        TILE(t,     af03A, bfA, af03B, bfB, r0, r1, r2)
        TILE(t + 1, af03B, bfB, af03A, bfA, r1, r2, r0)
        int8_t* tmp = r0; r0 = r2; r2 = r1; r1 = tmp;   // advance ring by 2
    }

    // ---- epilogue: C/D col = lane&15, row = (lane>>4)*4 + reg (dtype-indep) ----
    const int row0 = bm * BM + wm * 128 + q * 4;
    const int col0 = bn * BN + wn * 64 + r16;
    float sxv[8][4];
#pragma unroll
    for (int fr = 0; fr < 8; ++fr)
#pragma unroll
        for (int r = 0; r < 4; ++r)
            sxv[fr][r] = sx[row0 + fr * 16 + r];
#pragma unroll
    for (int fc = 0; fc < 4; ++fc) {
        const int n  = col0 + fc * 16;
        const float sc = scales[n];
        const float bi = bias[n];
#pragma unroll
        for (int fr = 0; fr < 8; ++fr) {
            const int m = row0 + fr * 16;
#pragma unroll
            for (int r = 0; r < 4; ++r)
                C[(size_t)(m + r) * N_OUT + n] =
                    (float)acc[fr][fc][r] * (sxv[fr][r] * sc) + bi;
        }
    }
}

// ---------- launch ----------

extern "C" void kernel_launch(void* const* d_in, const int* in_sizes, int n_in,
                              void* d_out, int out_size, void* d_ws, size_t ws_size,
                              hipStream_t stream) {
    const float* x      = (const float*)d_in[0];
    const int*   wq     = (const int*)d_in[1];
    const float* scales = (const float*)d_in[2];
    const float* bias   = (const float*)d_in[3];
    float*       out    = (float*)d_out;

    int8_t* xq = (int8_t*)d_ws;                               // 32 MiB
    int8_t* wb = xq + (size_t)M_TOK * K_IN;                   // 16 MiB
    float*  sx = (float*)(wb + (size_t)N_OUT * K_IN);         // 32 KiB
    // ws needed: 48 MiB + 32 KiB

    quant_x_kernel<<<M_TOK, 256, 0, stream>>>(x, xq, sx);
    const int nw16 = (N_OUT * K_IN) / 16;   // 1048576
    quant_w_kernel<<<nw16 / 256, 256, 0, stream>>>(wq, wb, nw16);

    const int grid = (M_TOK / BM) * (N_OUT / BN);   // 32 * 16 = 512
    gemm_i8_kernel<<<grid, 512, 0, stream>>>(xq, wb, sx, scales, bias, out);
}

// Round 17
// 188.555 us; speedup vs baseline: 1.8968x; 1.0527x over previous
//
#include <hip/hip_runtime.h>
#include <stdint.h>

// Problem constants (from reference setup_inputs)
#define M_TOK 8192
#define N_OUT 4096
#define K_IN  4096

// INT8 GEMM: 256x256 tile, BK=128, double-buffered LDS (128 KiB), 8 waves 2x4.
// W is EXACTLY int8 (reference stores int8 values in int32); x quantized
// per-token to int8 (sx = rowmax/127). Inner product exact in int32.
// This is the R14 kernel verbatim (measured 140us, absmax 4.5) -- the best
// verified GEMM after the full schedule-lever sweep (R6/R7/R16 neutral,
// R10/R11/R15 spill, R13 worse). Only the prepass is changed: both input
// conversions fused into ONE launch (block-range split).
#define BM 256
#define BN 256
#define BK 128
#define NT (K_IN / BK)            // 32 K-tiles
#define SEC 16384                 // bytes per k-slice section (256 rows x 64 B)
#define BUF 65536                 // bytes per buffer (A_s0|A_s1|B_s0|B_s1)

typedef int intx4 __attribute__((ext_vector_type(4)));

#define MFMAI8 __builtin_amdgcn_mfma_i32_16x16x64_i8

// ---------- helpers ----------

// async global->LDS, 16 bytes per lane. LDS side is wave-uniform base + lane*16.
__device__ __forceinline__ void async_copy16(const void* g, void* l) {
    __builtin_amdgcn_global_load_lds(
        (__attribute__((address_space(1))) void*)(g),
        (__attribute__((address_space(3))) void*)(l),
        16, 0, 0);
}

// ---------- fused pre-pass: x fp32 -> int8 per-token AND W int32 -> int8 ----------
// Blocks [0, M_TOK): quantize one x row each (sx = rowmax/127, RNE).
// Blocks [M_TOK, M_TOK + NWB): pack 16 W elements per thread (EXACT).
// One launch instead of two: the small W-pack (80 MiB) rides in the x-quant's
// (160 MiB) bandwidth shadow and one launch gap is removed.

#define NWB 4096   // W-pack blocks: (N_OUT*K_IN/16) / 256

__global__ void prep_kernel(const float* __restrict__ x,
                            const int* __restrict__ wq,
                            int8_t* __restrict__ xq,
                            float* __restrict__ sx,
                            int8_t* __restrict__ wb) {
    const int tid = threadIdx.x;

    if (blockIdx.x < M_TOK) {
        // ---- x row quantization ----
        const int row = blockIdx.x;
        const float4* p = (const float4*)(x + (size_t)row * K_IN + tid * 16);
        float4 v0 = p[0], v1 = p[1], v2 = p[2], v3 = p[3];

        float m = fabsf(v0.x);
        m = fmaxf(m, fabsf(v0.y)); m = fmaxf(m, fabsf(v0.z)); m = fmaxf(m, fabsf(v0.w));
        m = fmaxf(m, fabsf(v1.x)); m = fmaxf(m, fabsf(v1.y));
        m = fmaxf(m, fabsf(v1.z)); m = fmaxf(m, fabsf(v1.w));
        m = fmaxf(m, fabsf(v2.x)); m = fmaxf(m, fabsf(v2.y));
        m = fmaxf(m, fabsf(v2.z)); m = fmaxf(m, fabsf(v2.w));
        m = fmaxf(m, fabsf(v3.x)); m = fmaxf(m, fabsf(v3.y));
        m = fmaxf(m, fabsf(v3.z)); m = fmaxf(m, fabsf(v3.w));

#pragma unroll
        for (int off = 32; off; off >>= 1) m = fmaxf(m, __shfl_xor(m, off));
        __shared__ float wmax[4];
        if ((tid & 63) == 0) wmax[tid >> 6] = m;
        __syncthreads();
        m = fmaxf(fmaxf(wmax[0], wmax[1]), fmaxf(wmax[2], wmax[3]));
        m = fmaxf(m, 1e-20f);

        const float rs = 127.0f / m;
        if (tid == 0) sx[row] = m * (1.0f / 127.0f);

        union { int4 v; int8_t c[16]; } u;
        u.c[0]  = (int8_t)__float2int_rn(v0.x * rs);
        u.c[1]  = (int8_t)__float2int_rn(v0.y * rs);
        u.c[2]  = (int8_t)__float2int_rn(v0.z * rs);
        u.c[3]  = (int8_t)__float2int_rn(v0.w * rs);
        u.c[4]  = (int8_t)__float2int_rn(v1.x * rs);
        u.c[5]  = (int8_t)__float2int_rn(v1.y * rs);
        u.c[6]  = (int8_t)__float2int_rn(v1.z * rs);
        u.c[7]  = (int8_t)__float2int_rn(v1.w * rs);
        u.c[8]  = (int8_t)__float2int_rn(v2.x * rs);
        u.c[9]  = (int8_t)__float2int_rn(v2.y * rs);
        u.c[10] = (int8_t)__float2int_rn(v2.z * rs);
        u.c[11] = (int8_t)__float2int_rn(v2.w * rs);
        u.c[12] = (int8_t)__float2int_rn(v3.x * rs);
        u.c[13] = (int8_t)__float2int_rn(v3.y * rs);
        u.c[14] = (int8_t)__float2int_rn(v3.z * rs);
        u.c[15] = (int8_t)__float2int_rn(v3.w * rs);
        ((int4*)(xq + (size_t)row * K_IN))[tid] = u.v;
    } else {
        // ---- W pack: int32 (int8-valued) -> int8, exact ----
        const int i = (blockIdx.x - M_TOK) * 256 + tid;   // 16 elements each
        const int4* p = (const int4*)wq + (size_t)i * 4;
        int4 a = p[0], b = p[1], c = p[2], d = p[3];
        union { int4 v; int8_t q[16]; } u;
        u.q[0]  = (int8_t)a.x; u.q[1]  = (int8_t)a.y; u.q[2]  = (int8_t)a.z; u.q[3]  = (int8_t)a.w;
        u.q[4]  = (int8_t)b.x; u.q[5]  = (int8_t)b.y; u.q[6]  = (int8_t)b.z; u.q[7]  = (int8_t)b.w;
        u.q[8]  = (int8_t)c.x; u.q[9]  = (int8_t)c.y; u.q[10] = (int8_t)c.z; u.q[11] = (int8_t)c.w;
        u.q[12] = (int8_t)d.x; u.q[13] = (int8_t)d.y; u.q[14] = (int8_t)d.z; u.q[15] = (int8_t)d.w;
        ((int4*)wb)[i] = u.v;
    }
}

// ---------- GEMM: C[m][n] = sx[m]*scales[n]*(sum_k xq*wq) + bias[n] ----------
// R6's verified 4-phase single-sync skeleton on i8 / BK=128 (R14, 140us).
// mfma_i32_16x16x64_i8: A row = lane&15, k = (lane>>4)*16 + j; C/D layout
// dtype-independent (col = lane&15, row = (lane>>4)*4 + reg). Per wave per
// K=128 tile: 24 ds_read_b128 + 64 MFMA. NT = 32.
//
// Ledger (DS in-order per wave; stage = 8 gloads in P1/P2):
//  P1: stage A(t+1) s0,s1 | read A47s0->afB (4) | lgkm(4) [drains prev 8] |
//      MM03(afA,bfA)   [slice s0]
//  P2: stage B(t+1) s0,s1 | read A03s1->afA, Bs1->bfB (8) | lgkm(8) |
//      MM47(afB,bfA)   [s0]
//  P3: read A47s1->afB (4) | lgkm(4) | MM03(afA,bfB)   [s1]
//  P4: vmcnt(0)+lgkm(0) [stages issued 2-3 phases earlier - latency-covered
//      (R16 proved counted vmcnt gains nothing here)] | BARRIER |
//      read A03s0',Bs0' (8, next buf) | MM47(afB,bfB)  [s1]
// Hazards verified: all buf(t) reads lgkm-drained before the boundary
// barrier; stage(t+2) issues after it; buf(t+1) reads follow every wave's
// vmcnt(0)+barrier.
//
// LDS: byte sections A_s0|A_s1|B_s0|B_s1 (16 KiB each = 256 rows x 64 B),
// PAIR-ROW swizzle (HW-verified 0 conflicts): pair p = row>>1 (128 B) holds
// rows {2p,2p+1}; 16 B chunk (p,c): cg = c ^ (p&7); inverse on the per-lane
// GLOBAL source, linear LDS dest. Every ds_read_b128 covers one contiguous
// 1 KiB window exactly once (the R5 lesson).

__global__ __launch_bounds__(512, 2)
void gemm_i8_kernel(const int8_t* __restrict__ A,
                    const int8_t* __restrict__ B,
                    const float* __restrict__ sx,
                    const float* __restrict__ scales,
                    const float* __restrict__ bias,
                    float* __restrict__ C) {
    __shared__ __align__(16) int8_t lds[2 * BUF];   // 128 KiB

    const int tid = threadIdx.x;

    // T1: bijective XCD swizzle (nwg = 512, divisible by 8), bn-fastest.
    const int nwg = (M_TOK / BM) * (N_OUT / BN);   // 32*16 = 512
    const int cpx = nwg / 8;                        // 64
    const int wg  = (blockIdx.x % 8) * cpx + blockIdx.x / 8;
    const int bn  = wg & 15;                        // N_OUT/BN = 16
    const int bm  = wg >> 4;                        // 0..31

    const int lane = tid & 63;
    const int wave = tid >> 6;          // 0..7
    const int wm   = wave >> 2;         // 0..1 -> rows wm*128
    const int wn   = wave & 3;          // 0..3 -> cols wn*64

    // ---- staging addressing (pair-row inverse swizzle, bytes) ----
    // One issue = 512 lanes x 16 B = 8 KiB = 64 pairs = 128 rows of a 64B slice.
    const int t8 = tid >> 3;                        // 0..63
    const int cg = (tid & 7) ^ (t8 & 7);            // unswizzled chunk in pair
    const int grow0 = 2 * t8 + (cg >> 2);           // row within 128-row issue
    const int gcol0 = (cg & 3) * 16;                // bytes within 64B slice
    const int8_t* aP = A + (size_t)(bm * BM + grow0) * K_IN + gcol0;
    const int8_t* bP = B + (size_t)(bn * BN + grow0) * K_IN + gcol0;

    auto stA = [&](int tt, int s) {
        int8_t* d = &lds[(tt & 1) * BUF + s * SEC + tid * 16];
        const int8_t* g = aP + (size_t)tt * BK + s * 64;
        async_copy16(g, d);
        async_copy16(g + (size_t)128 * K_IN, d + 8192);
    };
    auto stB = [&](int tt, int s) {
        int8_t* d = &lds[(tt & 1) * BUF + 2 * SEC + s * SEC + tid * 16];
        const int8_t* g = bP + (size_t)tt * BK + s * 64;
        async_copy16(g, d);
        async_copy16(g + (size_t)128 * K_IN, d + 8192);
    };

    // ---- fragment read addressing ----
    // Frag row R: pair p = R>>1, chunk c = ((R&1)*4 + q) ^ ((R>>1)&7), 16 B.
    const int r16 = lane & 15;
    const int q   = lane >> 4;                      // k-chunk (16 B) in slice
    const int cr  = (((r16 & 1) << 2) + q) ^ ((r16 >> 1) & 7);
    const int aOff = (wm * 64 + (r16 >> 1)) * 128 + cr * 16;
    const int bOff = 2 * SEC + (wn * 32 + (r16 >> 1)) * 128 + cr * 16;

    intx4 acc[8][4] = {};
    intx4 afA[4], afB[4], bfA[4], bfB[4];

#define RD_A03(dst, base, s)                                                   \
    { _Pragma("unroll") for (int i = 0; i < 4; ++i)                            \
        dst[i] = *(const intx4*)((base) + (s) * SEC + aOff + i * 1024); }
#define RD_A47(dst, base, s)                                                   \
    { _Pragma("unroll") for (int i = 0; i < 4; ++i)                            \
        dst[i] = *(const intx4*)((base) + (s) * SEC + aOff + (4 + i) * 1024); }
#define RD_BF(dst, base, s)                                                    \
    { _Pragma("unroll") for (int j = 0; j < 4; ++j)                            \
        dst[j] = *(const intx4*)((base) + (s) * SEC + bOff + j * 1024); }
#define MM03(af, bf)                                                           \
    { __builtin_amdgcn_s_setprio(1);                                           \
      _Pragma("unroll") for (int i = 0; i < 4; ++i)                            \
          _Pragma("unroll") for (int j = 0; j < 4; ++j)                        \
              acc[i][j] = MFMAI8(af[i], bf[j], acc[i][j], 0, 0, 0);            \
      __builtin_amdgcn_s_setprio(0); }
#define MM47(af, bf)                                                           \
    { __builtin_amdgcn_s_setprio(1);                                           \
      _Pragma("unroll") for (int i = 0; i < 4; ++i)                            \
          _Pragma("unroll") for (int j = 0; j < 4; ++j)                        \
              acc[4 + i][j] = MFMAI8(af[i], bf[j], acc[4 + i][j], 0, 0, 0);    \
      __builtin_amdgcn_s_setprio(0); }
#define SBAR __builtin_amdgcn_sched_barrier(0)

    // ---- prologue: stage tile 0, publish, read s0 frags (8 left in flight) ----
    stA(0, 0); stB(0, 0); stA(0, 1); stB(0, 1);
    asm volatile("s_waitcnt vmcnt(0)" ::: "memory");
    __builtin_amdgcn_s_barrier();
    asm volatile("" ::: "memory");
    RD_A03(afA, lds, 0);
    RD_BF(bfA, lds, 0);

#pragma unroll 1
    for (int t = 0; t < NT; ++t) {
        const int8_t* Lb  = lds + (t & 1) * BUF;
        const int8_t* Lb2 = lds + ((t + 1) & 1) * BUF;
        const bool pf = (t + 1 < NT);

        // ---- P1: stage A(t+1) | read A47s0 | MM03(afA,bfA) ----
        if (pf) { stA(t + 1, 0); stA(t + 1, 1); }
        RD_A47(afB, Lb, 0);
        asm volatile("s_waitcnt lgkmcnt(4)" ::: "memory");
        SBAR;
        MM03(afA, bfA);

        // ---- P2: stage B(t+1) | read A03s1, Bs1 | MM47(afB,bfA) ----
        if (pf) { stB(t + 1, 0); stB(t + 1, 1); }
        RD_A03(afA, Lb, 1);
        RD_BF(bfB, Lb, 1);
        asm volatile("s_waitcnt lgkmcnt(8)" ::: "memory");
        SBAR;
        MM47(afB, bfA);

        // ---- P3: read A47s1 | MM03(afA,bfB) ----
        RD_A47(afB, Lb, 1);
        asm volatile("s_waitcnt lgkmcnt(4)" ::: "memory");
        SBAR;
        MM03(afA, bfB);

        // ---- P4: boundary sync | read next s0 frags | MM47(afB,bfB) ----
        asm volatile("s_waitcnt vmcnt(0) lgkmcnt(0)" ::: "memory");
        __builtin_amdgcn_s_barrier();
        asm volatile("" ::: "memory");
        if (pf) {
            RD_A03(afA, Lb2, 0);
            RD_BF(bfA, Lb2, 0);
        }
        SBAR;
        MM47(afB, bfB);
    }

    // ---- epilogue: C/D col = lane&15, row = (lane>>4)*4 + reg (dtype-indep) ----
    const int row0 = bm * BM + wm * 128 + q * 4;
    const int col0 = bn * BN + wn * 64 + r16;
    float sxv[8][4];
#pragma unroll
    for (int fr = 0; fr < 8; ++fr)
#pragma unroll
        for (int r = 0; r < 4; ++r)
            sxv[fr][r] = sx[row0 + fr * 16 + r];
#pragma unroll
    for (int fc = 0; fc < 4; ++fc) {
        const int n  = col0 + fc * 16;
        const float sc = scales[n];
        const float bi = bias[n];
#pragma unroll
        for (int fr = 0; fr < 8; ++fr) {
            const int m = row0 + fr * 16;
#pragma unroll
            for (int r = 0; r < 4; ++r)
                C[(size_t)(m + r) * N_OUT + n] =
                    (float)acc[fr][fc][r] * (sxv[fr][r] * sc) + bi;
        }
    }
}

// ---------- launch ----------

extern "C" void kernel_launch(void* const* d_in, const int* in_sizes, int n_in,
                              void* d_out, int out_size, void* d_ws, size_t ws_size,
                              hipStream_t stream) {
    const float* x      = (const float*)d_in[0];
    const int*   wq     = (const int*)d_in[1];
    const float* scales = (const float*)d_in[2];
    const float* bias   = (const float*)d_in[3];
    float*       out    = (float*)d_out;

    int8_t* xq = (int8_t*)d_ws;                               // 32 MiB
    int8_t* wb = xq + (size_t)M_TOK * K_IN;                   // 16 MiB
    float*  sx = (float*)(wb + (size_t)N_OUT * K_IN);         // 32 KiB
    // ws needed: 48 MiB + 32 KiB

    // Fused prepass: blocks [0,8192) quantize x rows; [8192,12288) pack W.
    prep_kernel<<<M_TOK + NWB, 256, 0, stream>>>(x, wq, xq, sx, wb);

    const int grid = (M_TOK / BM) * (N_OUT / BN);   // 32 * 16 = 512
    gemm_i8_kernel<<<grid, 512, 0, stream>>>(xq, wb, sx, scales, bias, out);
}